// Round 1
// 319.654 us; speedup vs baseline: 1.2741x; 1.2741x over previous
//
#include <hip/hip_runtime.h>
#include <hip/hip_bf16.h>

#define N_NODES 100000
#define N_EDGES 600000
#define D 128
#define SCAN_B 512
#define NBLK ((N_NODES + SCAN_B - 1) / SCAN_B)   // 196
#define ROWS_PB 32                               // dst rows per fused block
#define GSTR 132                                 // padded LDS row stride (floats)

typedef __attribute__((ext_vector_type(8))) short short8;
typedef __attribute__((ext_vector_type(8))) unsigned short ushort8;
typedef __attribute__((ext_vector_type(4))) unsigned int uint4v;
typedef __attribute__((ext_vector_type(4))) float f32x4;

union V8 { short8 s8; ushort8 u8; uint4v u4; };

__device__ __forceinline__ unsigned short f2bf(float f) {
    unsigned u = __float_as_uint(f);
    u += 0x7FFF + ((u >> 16) & 1);   // RNE
    return (unsigned short)(u >> 16);
}

// ---------------- weight fragments (unchanged) ----------------
__global__ void wfrag_kernel(const float* __restrict__ Wi,
                             const float* __restrict__ We,
                             unsigned short* __restrict__ Wfi,
                             unsigned short* __restrict__ Wfe) {
    int id = blockIdx.x * blockDim.x + threadIdx.x;   // 0..4095
    int mat = id >> 11;
    int idx = id & 2047;          // nt<<8 | ks<<6 | lane
    int lane = idx & 63;
    int ks = (idx >> 6) & 3;
    int nt = idx >> 8;
    int n = lane & 15, quad = lane >> 4;
    int row = nt * 16 + n;
    int k0 = ks * 32 + quad * 8;
    const float* W = mat ? We : Wi;
    unsigned short* Wf = mat ? Wfe : Wfi;
    #pragma unroll
    for (int j = 0; j < 8; ++j)
        Wf[idx * 8 + j] = f2bf(W[row * D + k0 + j]);
}

// ---------------- dst-sort preprocessing (CSR order) ----------------
__global__ void hist_kernel(const int* __restrict__ dst_idx,
                            unsigned* __restrict__ cnt) {
    int i = blockIdx.x * blockDim.x + threadIdx.x;
    if (i < N_EDGES) atomicAdd(&cnt[dst_idx[i]], 1u);
}

// per-block exclusive scan of cnt -> off (pristine, kept for CSR rowptr)
// and cur (scatter cursor); block totals -> bsum
__global__ __launch_bounds__(SCAN_B) void scanA_kernel(
    const unsigned* __restrict__ cnt, unsigned* __restrict__ off,
    unsigned* __restrict__ cur, unsigned* __restrict__ bsum) {
    int b = blockIdx.x, t = threadIdx.x;
    int i = b * SCAN_B + t;
    unsigned x = (i < N_NODES) ? cnt[i] : 0u;
    unsigned v = x;
    #pragma unroll
    for (int o = 1; o < 64; o <<= 1) {
        unsigned u = __shfl_up(v, o);
        if ((t & 63) >= o) v += u;
    }
    __shared__ unsigned wsum[SCAN_B / 64];
    if ((t & 63) == 63) wsum[t >> 6] = v;
    __syncthreads();
    if (t < SCAN_B / 64) {
        unsigned s = wsum[t];
        unsigned vv = s;
        #pragma unroll
        for (int o = 1; o < SCAN_B / 64; o <<= 1) {
            unsigned u = __shfl_up(vv, o);
            if (t >= o) vv += u;
        }
        wsum[t] = vv - s;   // exclusive wave offset
    }
    __syncthreads();
    unsigned inc = v + wsum[t >> 6];
    if (i < N_NODES) {
        unsigned ex = inc - x;       // block-local exclusive
        off[i] = ex;                 // pristine rowptr (block-local)
        cur[i] = ex;                 // scatter cursor
    }
    if (t == SCAN_B - 1) bsum[b] = inc;
}

// single block: exclusive scan of bsum (NBLK <= 256)
__global__ __launch_bounds__(256) void scanB_kernel(unsigned* __restrict__ bsum) {
    int t = threadIdx.x;
    unsigned x = (t < NBLK) ? bsum[t] : 0u;
    unsigned v = x;
    #pragma unroll
    for (int o = 1; o < 64; o <<= 1) {
        unsigned u = __shfl_up(v, o);
        if ((t & 63) >= o) v += u;
    }
    __shared__ unsigned wsum[4];
    if ((t & 63) == 63) wsum[t >> 6] = v;
    __syncthreads();
    if (t < 4) {
        unsigned s = wsum[t];
        unsigned vv = s;
        #pragma unroll
        for (int o = 1; o < 4; o <<= 1) {
            unsigned u = __shfl_up(vv, o);
            if (t >= o) vv += u;
        }
        wsum[t] = vv - s;
    }
    __syncthreads();
    unsigned inc = v + wsum[t >> 6];
    if (t < NBLK) bsum[t] = inc - x;   // exclusive
}

// scatter edges into dst-sorted order (uses cur as cursor; off stays pristine)
__global__ void scatter_kernel(const int* __restrict__ src_idx,
                               const int* __restrict__ dst_idx,
                               const float* __restrict__ ew,
                               unsigned* __restrict__ cur,
                               const unsigned* __restrict__ bsum,
                               int* __restrict__ sIp, int* __restrict__ dIp,
                               float* __restrict__ ewp) {
    int i = blockIdx.x * blockDim.x + threadIdx.x;
    if (i < N_EDGES) {
        int d = dst_idx[i];
        unsigned pos = atomicAdd(&cur[d], 1u) + bsum[d / SCAN_B];
        sIp[pos] = src_idx[i];
        dIp[pos] = d;
        ewp[pos] = ew[i];
    }
}

// ---------------- fused gather-sum + dual GEMM + leaky ----------------
// Algebra: out = leaky( (dst_x + g) @ Wi^T + (dst_x .* g) @ We^T )
// with g[d] = sum_{e: dst=d} ew_e * src_x[src_e].
// Block owns dst rows [d0, d0+32); its sorted-edge span [rp(d0), rp(d0+32))
// is split evenly over 16 quads (perfect load balance); run-carried partial
// sums flush into LDS g via ds f32 atomics (run boundaries only). Then two
// 16-row MFMA tiles, out written exactly once (no global atomics, no memset).
__global__ __launch_bounds__(256, 4) void fused_kernel(
    const float* __restrict__ src_x,
    const float* __restrict__ dst_x,
    const int* __restrict__ sIp, const int* __restrict__ dIp,
    const float* __restrict__ ewp,
    const unsigned* __restrict__ off, const unsigned* __restrict__ bsum,
    const unsigned short* __restrict__ Wfi,
    const unsigned short* __restrict__ Wfe,
    float* __restrict__ out) {
    __shared__ float g[ROWS_PB * GSTR];   // 32 x 132 f32 = 16.9 KB, pad kills bank conflicts

    int t = threadIdx.x, lane = t & 63, w = t >> 6;
    int quad = lane >> 4, nl = lane & 15;

    // B fragments: wave w owns output col blocks 2w, 2w+1 (layout as before)
    const short8* Wiv = (const short8*)Wfi;
    const short8* Wev = (const short8*)Wfe;
    short8 Bi[2][4], Be[2][4];
    #pragma unroll
    for (int ntl = 0; ntl < 2; ++ntl)
        #pragma unroll
        for (int ks = 0; ks < 4; ++ks) {
            Bi[ntl][ks] = Wiv[((2 * w + ntl) * 4 + ks) * 64 + lane];
            Be[ntl][ks] = Wev[((2 * w + ntl) * 4 + ks) * 64 + lane];
        }

    // zero LDS g
    for (int i = t; i < ROWS_PB * GSTR; i += 256) g[i] = 0.f;
    __syncthreads();

    int d0 = blockIdx.x * ROWS_PB;
    // CSR rowptr from pristine per-scanblock exclusive + block offsets
    unsigned start = off[d0] + bsum[d0 >> 9];
    int dend = d0 + ROWS_PB;
    unsigned end = (dend >= N_NODES) ? (unsigned)N_EDGES
                                     : (off[dend] + bsum[dend >> 9]);

    // ---- gather phase: 16 quads split the span evenly ----
    unsigned L = end - start;
    unsigned chunk = (L + 15) >> 4;
    int qid = t >> 4;                       // 0..15
    unsigned es = start + (unsigned)qid * chunk;
    unsigned ee = es + chunk; if (ee > end) ee = end;

    if (es < ee) {
        float4 a0 = {0.f, 0.f, 0.f, 0.f}, a1 = {0.f, 0.f, 0.f, 0.f};
        int run_dl = -1;
        int sN = sIp[es]; float wN = ewp[es]; int dlN = dIp[es] - d0;
        for (unsigned e = es; e < ee; ++e) {
            int s = sN; float wgt = wN; int dl = dlN;
            if (e + 1 < ee) {               // prefetch next edge metadata
                sN = sIp[e + 1]; wN = ewp[e + 1]; dlN = dIp[e + 1] - d0;
            }
            const float* rp = src_x + (size_t)s * D + nl * 8;
            float4 r0 = *(const float4*)rp;
            float4 r1 = *(const float4*)(rp + 4);
            if (dl != run_dl) {
                if (run_dl >= 0) {
                    float* gp = &g[run_dl * GSTR + nl * 8];
                    atomicAdd(gp + 0, a0.x); atomicAdd(gp + 1, a0.y);
                    atomicAdd(gp + 2, a0.z); atomicAdd(gp + 3, a0.w);
                    atomicAdd(gp + 4, a1.x); atomicAdd(gp + 5, a1.y);
                    atomicAdd(gp + 6, a1.z); atomicAdd(gp + 7, a1.w);
                }
                run_dl = dl;
                a0 = (float4){0.f, 0.f, 0.f, 0.f};
                a1 = (float4){0.f, 0.f, 0.f, 0.f};
            }
            a0.x += wgt * r0.x; a0.y += wgt * r0.y;
            a0.z += wgt * r0.z; a0.w += wgt * r0.w;
            a1.x += wgt * r1.x; a1.y += wgt * r1.y;
            a1.z += wgt * r1.z; a1.w += wgt * r1.w;
        }
        // final flush
        float* gp = &g[run_dl * GSTR + nl * 8];
        atomicAdd(gp + 0, a0.x); atomicAdd(gp + 1, a0.y);
        atomicAdd(gp + 2, a0.z); atomicAdd(gp + 3, a0.w);
        atomicAdd(gp + 4, a1.x); atomicAdd(gp + 5, a1.y);
        atomicAdd(gp + 6, a1.z); atomicAdd(gp + 7, a1.w);
    }
    __syncthreads();

    // ---- MFMA phase: two 16-row tiles; A1 = bf16(dst+g), A2 = bf16(dst*g) ----
    #pragma unroll
    for (int tl = 0; tl < 2; ++tl) {
        int r = tl * 16 + nl;                        // local row 0..31
        const float* xr = dst_x + (size_t)(d0 + r) * D + quad * 8;
        const float* gr = &g[r * GSTR + quad * 8];
        f32x4 acc[2];
        acc[0] = (f32x4){0.f, 0.f, 0.f, 0.f};
        acc[1] = (f32x4){0.f, 0.f, 0.f, 0.f};
        #pragma unroll
        for (int ks = 0; ks < 4; ++ks) {
            float4 f0 = *(const float4*)(xr + ks * 32);
            float4 f1 = *(const float4*)(xr + ks * 32 + 4);
            float4 g0 = *(const float4*)(gr + ks * 32);
            float4 g1 = *(const float4*)(gr + ks * 32 + 4);
            V8 a1v, a2v;
            a1v.u8[0] = f2bf(f0.x + g0.x); a2v.u8[0] = f2bf(f0.x * g0.x);
            a1v.u8[1] = f2bf(f0.y + g0.y); a2v.u8[1] = f2bf(f0.y * g0.y);
            a1v.u8[2] = f2bf(f0.z + g0.z); a2v.u8[2] = f2bf(f0.z * g0.z);
            a1v.u8[3] = f2bf(f0.w + g0.w); a2v.u8[3] = f2bf(f0.w * g0.w);
            a1v.u8[4] = f2bf(f1.x + g1.x); a2v.u8[4] = f2bf(f1.x * g1.x);
            a1v.u8[5] = f2bf(f1.y + g1.y); a2v.u8[5] = f2bf(f1.y * g1.y);
            a1v.u8[6] = f2bf(f1.z + g1.z); a2v.u8[6] = f2bf(f1.z * g1.z);
            a1v.u8[7] = f2bf(f1.w + g1.w); a2v.u8[7] = f2bf(f1.w * g1.w);
            acc[0] = __builtin_amdgcn_mfma_f32_16x16x32_bf16(a1v.s8, Bi[0][ks], acc[0], 0, 0, 0);
            acc[1] = __builtin_amdgcn_mfma_f32_16x16x32_bf16(a1v.s8, Bi[1][ks], acc[1], 0, 0, 0);
            acc[0] = __builtin_amdgcn_mfma_f32_16x16x32_bf16(a2v.s8, Be[0][ks], acc[0], 0, 0, 0);
            acc[1] = __builtin_amdgcn_mfma_f32_16x16x32_bf16(a2v.s8, Be[1][ks], acc[1], 0, 0, 0);
        }
        // store with fused leaky; C layout as node_mfma3 (verified)
        #pragma unroll
        for (int ntl = 0; ntl < 2; ++ntl)
            #pragma unroll
            for (int rr = 0; rr < 4; ++rr) {
                float v = acc[ntl][rr];
                v = v > 0.f ? v : 0.01f * v;
                out[(size_t)(d0 + tl * 16 + quad * 4 + rr) * D
                    + (2 * w + ntl) * 16 + nl] = v;
            }
    }
}

extern "C" void kernel_launch(void* const* d_in, const int* in_sizes, int n_in,
                              void* d_out, int out_size, void* d_ws, size_t ws_size,
                              hipStream_t stream) {
    const float* src_x = (const float*)d_in[0];
    const float* dst_x = (const float*)d_in[1];
    const int*   eidx  = (const int*)d_in[2];     // [2, E] flat: src then dst
    const float* ew    = (const float*)d_in[3];   // [E, 1]
    const float* Wi    = (const float*)d_in[4];   // [D, D]
    const float* We    = (const float*)d_in[5];   // [D, D]
    float* out = (float*)d_out;

    // ws layout
    char* wsb = (char*)d_ws;
    unsigned short* Wfi = (unsigned short*)(wsb);            // 32768 B
    unsigned short* Wfe = (unsigned short*)(wsb + 32768);    // 32768 B
    char* p = wsb + 65536;
    int*      sIp  = (int*)p;      p += (size_t)N_EDGES * 4;
    int*      dIp  = (int*)p;      p += (size_t)N_EDGES * 4;
    float*    ewp  = (float*)p;    p += (size_t)N_EDGES * 4;
    unsigned* cnt  = (unsigned*)p; p += (size_t)(NBLK * SCAN_B) * 4;
    unsigned* off  = (unsigned*)p; p += (size_t)(NBLK * SCAN_B) * 4;
    unsigned* cur  = (unsigned*)p; p += (size_t)(NBLK * SCAN_B) * 4;
    unsigned* bsum = (unsigned*)p;

    const int* src_idx = eidx;
    const int* dst_idx = eidx + N_EDGES;

    wfrag_kernel<<<16, 256, 0, stream>>>(Wi, We, Wfi, Wfe);

    // --- dst-sort preprocessing
    hipMemsetAsync(cnt, 0, (size_t)N_NODES * 4, stream);
    hist_kernel<<<(N_EDGES + 255) / 256, 256, 0, stream>>>(dst_idx, cnt);
    scanA_kernel<<<NBLK, SCAN_B, 0, stream>>>(cnt, off, cur, bsum);
    scanB_kernel<<<1, 256, 0, stream>>>(bsum);
    scatter_kernel<<<(N_EDGES + 255) / 256, 256, 0, stream>>>(
        src_idx, dst_idx, ew, cur, bsum, sIp, dIp, ewp);

    // --- fused gather-sum + dual GEMM + leaky (writes out exactly once)
    fused_kernel<<<N_NODES / ROWS_PB, 256, 0, stream>>>(
        src_x, dst_x, sIp, dIp, ewp, off, bsum, Wfi, Wfe, out);
}